// Round 3
// baseline (316.237 us; speedup 1.0000x reference)
//
#include <hip/hip_runtime.h>
#include <math.h>

// GNO2d spectral conv, pruned-DFT factorization (fp32 throughout).
// B=8, Ci=Co=32, T=128, X=256, P=3; modes: kt {0..15}u{112..127}, kx 0..15, kz 0..1.
typedef float2 F2;

__device__ __forceinline__ F2 cmul(F2 a, F2 b) {
    return make_float2(a.x * b.x - a.y * b.y, a.x * b.y + a.y * b.x);
}
__device__ __forceinline__ F2 cmac(F2 acc, F2 a, F2 b) {
    acc.x += a.x * b.x - a.y * b.y;
    acc.y += a.x * b.y + a.y * b.x;
    return acc;
}

#define TWO_PI 6.283185307179586f
#define SQRT3_2 0.8660254037844386f
#define SQRT3 1.7320508075688772f

// ---------------------------------------------------------------------------
// KW: pack weights [i][o][m1][kx][m3] (4 tensors) -> packed[m1][kx][kz][io] F2
// Coalesced reads; scattered 8B writes are absorbed by L2 (output 8 MB).
// ---------------------------------------------------------------------------
__global__ __launch_bounds__(256) void kw_pack(const float* __restrict__ w1re,
                                               const float* __restrict__ w1im,
                                               const float* __restrict__ w2re,
                                               const float* __restrict__ w2im,
                                               F2* __restrict__ p1,
                                               F2* __restrict__ p2) {
    const int tid = threadIdx.x;
    const int blk = blockIdx.x;          // 1536 blocks: 768 per tensor
    const bool second = blk >= 768;
    const float* re = second ? w2re : w1re;
    const float* im = second ? w2im : w1im;
    F2* dstp = second ? p2 : p1;
    const int base = (second ? blk - 768 : blk) * 1024;
#pragma unroll
    for (int j = 0; j < 4; ++j) {
        int e = base + tid + 256 * j;    // < 786432
        float rv = re[e], iv = im[e];
        int m3 = e % 3;
        int r = e / 3;
        int kx = r & 15;
        int m1 = (r >> 4) & 15;
        int io = r >> 8;                 // i*32+o
        if (m3 < 2) {
            dstp[(size_t)(((m1 * 16 + kx) * 2 + m3) * 1024 + io)] = make_float2(rv, iv);
        }
    }
}

// ---------------------------------------------------------------------------
// K1 v3: x [row=(b,i,t)][256][3] -> y [row][kz(2)][kx(16)] complex
// thread = (kz, rr, kxg, c8): 8 kx per thread (kx = kxg+2u), x = c8+8m (m<16),
// mirror-folded over x/x+128 with sign (-1)^kx = (-1)^kxg.
// c8-phase partials reduced via shfl_xor; y written fully coalesced.
// ---------------------------------------------------------------------------
__global__ __launch_bounds__(256, 5) void k1_fwd_x(const float* __restrict__ x,
                                                   F2* __restrict__ y) {
    __shared__ float xp0[8][264];   // pad: banks 8*rr + c8 distinct
    __shared__ F2    xp1[8][264];   // pad: 2-way max (free)
    __shared__ F2    twred[256];    // twiddles; reused as reduction buffer
    const int tid = threadIdx.x;
    const int blk = blockIdx.x;     // 8 rows per block, 4096 blocks

    {   // twiddle table tw[n] = e^{-2pi i n/256}
        float sv, cv;
        sincosf(-TWO_PI * (float)tid * (1.0f / 256.0f), &sv, &cv);
        twred[tid] = make_float2(cv, sv);
    }
    // p-stage into LDS
#pragma unroll
    for (int j = 0; j < 8; ++j) {
        int item = tid + 256 * j;           // 2048 = 8 rows * 256 x
        int row = item >> 8, xx = item & 255;
        const float* src = x + ((size_t)(blk * 8 + row) * 256 + xx) * 3;
        float a = src[0], b = src[1], c = src[2];
        xp0[row][xx] = a + b + c;
        xp1[row][xx] = make_float2(a - 0.5f * (b + c), SQRT3_2 * (c - b));
    }
    __syncthreads();

    const int c8 = tid & 7, kxg = (tid >> 3) & 1, rr = (tid >> 4) & 7, kz = tid >> 7;
    const float sgn = kxg ? -1.0f : 1.0f;

    F2 acc[8], w[8], stp[8];
#pragma unroll
    for (int u = 0; u < 8; ++u) {
        int kx = kxg + 2 * u;
        acc[u] = make_float2(0.f, 0.f);
        w[u] = twred[(kx * c8) & 255];     // e^{-2pi i kx c8/256}
        stp[u] = twred[(8 * kx) & 255];    // e^{-2pi i 8kx/256}
    }

    if (kz == 0) {
        const float* r0 = xp0[rr];
#pragma unroll 4
        for (int m = 0; m < 16; ++m) {
            int xx = c8 + 8 * m;
            float s = fmaf(sgn, r0[xx + 128], r0[xx]);
#pragma unroll
            for (int u = 0; u < 8; ++u) {
                acc[u].x = fmaf(s, w[u].x, acc[u].x);
                acc[u].y = fmaf(s, w[u].y, acc[u].y);
                w[u] = cmul(w[u], stp[u]);
            }
        }
    } else {
        const F2* r1 = xp1[rr];
#pragma unroll 4
        for (int m = 0; m < 16; ++m) {
            int xx = c8 + 8 * m;
            F2 a = r1[xx], b = r1[xx + 128];
            F2 s = make_float2(fmaf(sgn, b.x, a.x), fmaf(sgn, b.y, a.y));
#pragma unroll
            for (int u = 0; u < 8; ++u) {
                acc[u] = cmac(acc[u], s, w[u]);
                w[u] = cmul(w[u], stp[u]);
            }
        }
    }

    // butterfly-reduce over c8 (lanes differing in bits 0..2)
#pragma unroll
    for (int u = 0; u < 8; ++u) {
#pragma unroll
        for (int d = 1; d <= 4; d <<= 1) {
            acc[u].x += __shfl_xor(acc[u].x, d, 64);
            acc[u].y += __shfl_xor(acc[u].y, d, 64);
        }
    }
    __syncthreads();   // everyone done reading twred as twiddles
    if (c8 == 0) {
#pragma unroll
        for (int u = 0; u < 8; ++u)
            twred[((rr * 2 + kz) << 4) + kxg + 2 * u] = acc[u];
    }
    __syncthreads();
    // coalesced write: y[blk*256 + (rr*2+kz)*16 + kx]
    y[(size_t)blk * 256 + tid] = twred[tid];
}

// ---------------------------------------------------------------------------
// K2a: y [(b,i),t,kz,kx] -> x_ft [b][s(32)][kz][kx][i] complex
// x_ft[s] = sum_t y[t] e^{-2pi i kt(s) t/128}, kt = s (s<16) else 96+s
// ---------------------------------------------------------------------------
__global__ __launch_bounds__(256) void k2a_fwd_t(const F2* __restrict__ y,
                                                 F2* __restrict__ xft) {
    __shared__ F2 yL[128][16];
    const int tid = threadIdx.x;
    const int bi = blockIdx.x >> 1, kz = blockIdx.x & 1;   // 512 blocks
#pragma unroll
    for (int j = 0; j < 8; ++j) {
        int item = tid + 256 * j;       // 2048 = 128 t * 16 kx
        int t = item >> 4, kx = item & 15;
        yL[t][kx] = y[((size_t)(bi * 128 + t) * 2 + kz) * 16 + kx];
    }
    __syncthreads();

    const int kx = tid & 15, sg = tid >> 4;   // sg in [0,16)
    F2 rotA = make_float2(1.f, 0.f), rotB = make_float2(1.f, 0.f), stepA, stepB;
    sincosf(-TWO_PI * (float)sg * (1.0f / 128.0f), &stepA.y, &stepA.x);
    sincosf(-TWO_PI * (float)(112 + sg) * (1.0f / 128.0f), &stepB.y, &stepB.x);
    F2 accA = make_float2(0.f, 0.f), accB = make_float2(0.f, 0.f);
    for (int t = 0; t < 128; ++t) {
        F2 v = yL[t][kx];
        accA = cmac(accA, v, rotA);
        accB = cmac(accB, v, rotB);
        rotA = cmul(rotA, stepA);
        rotB = cmul(rotB, stepB);
    }
    const int b = bi >> 5, i = bi & 31;
    xft[(((size_t)(b * 32 + sg) * 2 + kz) * 16 + kx) * 32 + i] = accA;
    xft[(((size_t)(b * 32 + (16 + sg)) * 2 + kz) * 16 + kx) * 32 + i] = accB;
}

// ---------------------------------------------------------------------------
// K2b: mode mix. block per (s,kx) (512 blocks); thread = (b,o).
// Weights from packed [m1][kx][kz][io] -> fully coalesced LDS fill.
// ---------------------------------------------------------------------------
__global__ __launch_bounds__(256) void k2b_mix(const F2* __restrict__ xft,
                                               const F2* __restrict__ p1,
                                               const F2* __restrict__ p2,
                                               F2* __restrict__ blkout) {
    __shared__ F2 xL[512];            // [b][kz][i]
    __shared__ F2 wcL[2][1024];       // [kz][io]
    const int tid = threadIdx.x;
    const int s = blockIdx.x >> 4, kx = blockIdx.x & 15;
#pragma unroll
    for (int j = 0; j < 2; ++j) {
        int item = tid + 256 * j;     // 512 = 8b * 2kz * 32i
        int b = item >> 6, kz = (item >> 5) & 1, i = item & 31;
        xL[item] = xft[(((size_t)(b * 32 + s) * 2 + kz) * 16 + kx) * 32 + i];
    }
    const F2* wsrc = (s < 16) ? p1 : p2;
    const int m1 = s & 15;
    const size_t wbase = (size_t)(m1 * 16 + kx) * 2048;
#pragma unroll
    for (int j = 0; j < 8; ++j) {
        int item = tid + 256 * j;     // 2048 = 2kz * 1024io
        wcL[0][item] = wsrc[wbase + item];   // flat: [kz][io]
    }
    __syncthreads();

    const int b = tid >> 5, o = tid & 31;
#pragma unroll
    for (int kz = 0; kz < 2; ++kz) {
        F2 acc = make_float2(0.f, 0.f);
        for (int i = 0; i < 32; ++i) {
            F2 xv = xL[(b * 2 + kz) * 32 + i];     // broadcast across o
            F2 wv = wcL[kz][i * 32 + o];
            acc.x += xv.x * wv.x - xv.y * wv.y;
            acc.y += xv.x * wv.y + xv.y * wv.x;
        }
        blkout[(((size_t)(b * 32 + o) * 32 + s) * 2 + kz) * 16 + kx] = acc;
    }
}

// ---------------------------------------------------------------------------
// K2c3: fused inverse-t + inverse-x + irfft(n=3) epilogue.
// block = (bo, tc) (2048 blocks), 16 t-rows per block; h lives only in LDS.
// Output staged in LDS and stored as coalesced float4.
// ---------------------------------------------------------------------------
__global__ __launch_bounds__(256, 4) void k2c3(const F2* __restrict__ bkin,
                                               float* __restrict__ out) {
    __shared__ F2 bL[1024];        // [s][col], col = kz*16+kx
    __shared__ F2 hL[16][33];      // [t_loc][col], +1 pad
    __shared__ float oL[2][772];   // 2 output rows staging
    const int tid = threadIdx.x;
    const int bo = blockIdx.x >> 3, tc = blockIdx.x & 7;
#pragma unroll
    for (int j = 0; j < 4; ++j) {
        int item = tid + 256 * j;
        bL[item] = bkin[(size_t)bo * 1024 + item];
    }
    __syncthreads();

    // ---- phase 1: inverse t for 16 rows ----
    {
        const int col = tid & 31, tl = tid >> 5;   // tl in [0,8)
        F2 accA[2], accB[2], w[2], stp[2];
#pragma unroll
        for (int q = 0; q < 2; ++q) {
            accA[q] = make_float2(0.f, 0.f);
            accB[q] = make_float2(0.f, 0.f);
            w[q] = make_float2(1.f, 0.f);
            int t = tc * 16 + tl + 8 * q;
            sincosf(TWO_PI * (float)t * (1.0f / 128.0f), &stp[q].y, &stp[q].x);
        }
        for (int sp = 0; sp < 16; ++sp) {
            F2 bA = bL[sp * 32 + col];
            F2 bB = bL[(16 + sp) * 32 + col];
#pragma unroll
            for (int q = 0; q < 2; ++q) {
                accA[q] = cmac(accA[q], bA, w[q]);
                accB[q] = cmac(accB[q], bB, w[q]);
                w[q] = cmul(w[q], stp[q]);
            }
        }
        F2 ph;   // e^{+2pi i 112 t/128} = e^{-2pi i (t mod 8)/8}, t mod 8 = tl
        sincosf(-TWO_PI * (float)tl * (1.0f / 8.0f), &ph.y, &ph.x);
#pragma unroll
        for (int q = 0; q < 2; ++q) {
            F2 r = cmac(accA[q], ph, accB[q]);
            hL[tl + 8 * q][col] = r;
        }
    }
    __syncthreads();

    // ---- phase 2: inverse x + p-epilogue, 2 rows per iteration ----
    const int xx = tid & 127, half = tid >> 7;
    F2 rot;
    sincosf(TWO_PI * (float)xx * (1.0f / 256.0f), &rot.y, &rot.x);
    const float n = 1.0f / 98304.0f;   // 1/(128*256*3)
    const size_t outbase = (size_t)(bo * 128 + tc * 16) * 768;

    for (int tt = 0; tt < 8; ++tt) {
        const int t_loc = 2 * tt + half;
        const F2* hrow = hL[t_loc];
        F2 w = make_float2(1.f, 0.f);
        float e0 = 0.f, o0 = 0.f;
        F2 e1 = make_float2(0.f, 0.f), o1 = make_float2(0.f, 0.f);
#pragma unroll
        for (int k2 = 0; k2 < 8; ++k2) {
            {   // even kx = 2*k2
                F2 h0 = hrow[2 * k2], h1 = hrow[16 + 2 * k2];
                e0 += h0.x * w.x - h0.y * w.y;
                e1.x += h1.x * w.x - h1.y * w.y;
                e1.y += h1.x * w.y + h1.y * w.x;
                w = cmul(w, rot);
            }
            {   // odd kx = 2*k2+1
                F2 h0 = hrow[2 * k2 + 1], h1 = hrow[16 + 2 * k2 + 1];
                o0 += h0.x * w.x - h0.y * w.y;
                o1.x += h1.x * w.x - h1.y * w.y;
                o1.y += h1.x * w.y + h1.y * w.x;
                w = cmul(w, rot);
            }
        }
        float* dst = oL[half];
        {
            float g0 = e0 + o0, g1r = e1.x + o1.x, g1i = e1.y + o1.y;
            dst[xx * 3 + 0] = n * (g0 + 2.f * g1r);
            dst[xx * 3 + 1] = n * (g0 - g1r - SQRT3 * g1i);
            dst[xx * 3 + 2] = n * (g0 - g1r + SQRT3 * g1i);
        }
        {
            float g0 = e0 - o0, g1r = e1.x - o1.x, g1i = e1.y - o1.y;
            int xb = xx + 128;
            dst[xb * 3 + 0] = n * (g0 + 2.f * g1r);
            dst[xb * 3 + 1] = n * (g0 - g1r - SQRT3 * g1i);
            dst[xb * 3 + 2] = n * (g0 - g1r + SQRT3 * g1i);
        }
        __syncthreads();
        if (tid < 192) {
#pragma unroll
            for (int r = 0; r < 2; ++r) {
                float4 v = *(const float4*)&oL[r][tid * 4];
                *(float4*)&out[outbase + (size_t)(2 * tt + r) * 768 + tid * 4] = v;
            }
        }
        __syncthreads();
    }
}

// ---------------------------------------------------------------------------
extern "C" void kernel_launch(void* const* d_in, const int* in_sizes, int n_in,
                              void* d_out, int out_size, void* d_ws, size_t ws_size,
                              hipStream_t stream) {
    const float* x    = (const float*)d_in[0];
    const float* w1re = (const float*)d_in[1];
    const float* w1im = (const float*)d_in[2];
    const float* w2re = (const float*)d_in[3];
    const float* w2im = (const float*)d_in[4];
    float* out = (float*)d_out;

    // ws layout (F2 units): y 1048576 | xft 262144 | bk 262144 | p1 524288 | p2 524288
    F2* y   = (F2*)d_ws;
    F2* xft = y + 1048576;
    F2* bk  = xft + 262144;
    F2* p1  = bk + 262144;
    F2* p2  = p1 + 524288;

    hipLaunchKernelGGL(kw_pack,   dim3(1536), dim3(256), 0, stream,
                       w1re, w1im, w2re, w2im, p1, p2);
    hipLaunchKernelGGL(k1_fwd_x,  dim3(4096), dim3(256), 0, stream, x, y);
    hipLaunchKernelGGL(k2a_fwd_t, dim3(512),  dim3(256), 0, stream, y, xft);
    hipLaunchKernelGGL(k2b_mix,   dim3(512),  dim3(256), 0, stream, xft, p1, p2, bk);
    hipLaunchKernelGGL(k2c3,      dim3(2048), dim3(256), 0, stream, bk, out);
}